// Round 4
// baseline (155.561 us; speedup 1.0000x reference)
//
#include <hip/hip_runtime.h>
#include <hip/hip_bf16.h>

#define BATCH 16
#define CI 64
#define CO 64
#define H 128
#define W 128
#define HO 126
#define WO 126
#define HW (H * W)

typedef short bfrag __attribute__((ext_vector_type(8)));   // 8 bf16 = 4 VGPRs
typedef float ffrag __attribute__((ext_vector_type(4)));   // 4 fp32 acc

static __device__ __forceinline__ unsigned short f2bf(float f) {
    unsigned u = __float_as_uint(f);
    u += 0x7fffu + ((u >> 16) & 1u);      // RNE
    return (unsigned short)(u >> 16);
}

// prepass: w[b][co][ci][dy][dx] fp32 -> w_t[b][s][co][ci] bf16  (s = dy*3+dx)
__global__ void wt_prepass(const float* __restrict__ w, unsigned short* __restrict__ w_t) {
    int i = blockIdx.x * 256 + threadIdx.x;          // 589824 total
    int ci = i & 63;
    int co = (i >> 6) & 63;
    int bs = i >> 12;
    int b = bs / 9, s = bs - b * 9;
    w_t[i] = f2bf(w[(((b * 64 + co) * 64 + ci) * 9) + s]);
}

// cvt + swizzled LDS write of one staged row fragment (R2/R3-verified:
// SQ_LDS_BANK_CONFLICT == 0 on both the ds_write and ds_read sides).
static __device__ __forceinline__ void stage_write(unsigned short* __restrict__ slabp,
                                                   const float4* __restrict__ v,
                                                   int st_o, int st_cg) {
    #pragma unroll
    for (int k = 0; k < 4; ++k) {
        const int col = st_cg * 4 + k;
        unsigned int u[4];
        #pragma unroll
        for (int e = 0; e < 4; ++e) {
            __hip_bfloat162 h2 = __float22bfloat162_rn(make_float2(
                ((const float*)&v[2 * e])[k], ((const float*)&v[2 * e + 1])[k]));
            u[e] = *(unsigned int*)&h2;          // low = even ci
        }
        *(uint4*)&slabp[(col * 8 + (st_o ^ (col & 7))) * 8] = *(const uint4*)u;
    }
}

// Ring-pipelined dynconv, DISTANCE-2 prefetch (R4):
//  - R3 post-mortem: distance-1 made every unit end in a ~7k-cyc vmcnt stall
//    (32 KB loads + 32 KB older stores need ~12.5k cyc fair-share service but
//    the compute phase is only ~5k) -> HBM duty 46%, 2.84 TB/s.
//  - Now loads for row j+4 issue at unit j; stage_write(j+3) at unit j uses
//    loads issued at unit j-1 (a full unit of service time -> no stall).
//    In-order vmcnt: loads(j+3) are OLDER than stores(j-1)+loads(j+4), so the
//    wait is counted (vmcnt~40) and never drains the in-flight traffic.
//  - LDS ring of 5 row-slabs (80 KB): unit j reads slabs (j..j+2)%5, writes
//    (j+3)%5 (disjoint); overwritten row j-2 last read 2 barriers ago.
//    One raw s_barrier (lgkmcnt-only) per unit keeps stores/loads in flight.
//  - vA/vB named double-buffer, loop unrolled by 2 (no runtime reg indexing).
__launch_bounds__(256, 2)
__global__ void dynconv_fused(const float* __restrict__ x,
                              const unsigned short* __restrict__ w_t,
                              const float* __restrict__ bias,
                              float* __restrict__ out) {
    __shared__ __align__(16) unsigned short xs[5 * 8192];   // 5 row-slabs x 16 KB

    const int tid = threadIdx.x;
    const int gx  = blockIdx.x;              // 0..31 row-ranges
    const int b   = blockIdx.y;
    const int y0  = gx * 4;
    const int nunits = (gx == 31) ? 2 : 4;   // 126 output rows total

    const int wave = tid >> 6, lane = tid & 63;
    const int l16 = lane & 15, lq = lane >> 4;

    // staging role: o fast, col-quad slow
    const int st_o  = tid & 7;
    const int st_cg = tid >> 3;              // 0..31

    const float* stp = x + (size_t)b * CI * HW + (size_t)(st_o * 8) * HW + st_cg * 4;

    // ---- A-frag preload: all 9 shifts x 2 ks for this wave's co-quarter
    const bfrag* wtb = (const bfrag*)w_t + (size_t)(b * 9) * 512;
    const int co_b = wave * 16 + l16;
    bfrag a[9][2];
    #pragma unroll
    for (int s = 0; s < 9; ++s)
        #pragma unroll
        for (int ks = 0; ks < 2; ++ks)
            a[s][ks] = wtb[s * 512 + co_b * 8 + ks * 4 + lq];

    float bv[4];
    #pragma unroll
    for (int r = 0; r < 4; ++r)
        bv[r] = bias[b * 64 + wave * 16 + lq * 4 + r];

    float4 vA[8], vB[8];

    // ---- prologue: stage rows y0..y0+2 into slabs 0..2; prefetch row y0+3->vA
    {
        float4 v[3][8];
        #pragma unroll
        for (int rr = 0; rr < 3; ++rr) {
            const float* p = stp + (size_t)(y0 + rr) * W;
            #pragma unroll
            for (int e = 0; e < 8; ++e) v[rr][e] = *(const float4*)(p + (size_t)e * HW);
        }
        {   // issue the distance-2 prefetch before the cvt waits on the rows above
            const float* p = stp + (size_t)(y0 + 3) * W;
            #pragma unroll
            for (int e = 0; e < 8; ++e) vA[e] = *(const float4*)(p + (size_t)e * HW);
        }
        #pragma unroll
        for (int rr = 0; rr < 3; ++rr)
            stage_write(&xs[rr * 8192], v[rr], st_o, st_cg);
    }
    asm volatile("s_waitcnt lgkmcnt(0)" ::: "memory");
    __builtin_amdgcn_s_barrier();
    __builtin_amdgcn_sched_barrier(0);

// one output-row unit: prefetch row jj+4 into VNEXT, compute row jj from slabs
// (jj..jj+2)%5, stage_write row jj+3 from VCUR, barrier, store row jj.
#define UNIT(J_, VCUR, VNEXT)                                                   \
    do {                                                                        \
        const int jj = (J_);                                                    \
        if (jj + 3 <= nunits) {                                                 \
            const float* p = stp + (size_t)(y0 + jj + 4) * W;                   \
            _Pragma("unroll") for (int e = 0; e < 8; ++e)                       \
                VNEXT[e] = *(const float4*)(p + (size_t)e * HW);                \
        }                                                                       \
        __builtin_amdgcn_sched_barrier(0);                                      \
        ffrag acc[8];                                                           \
        _Pragma("unroll") for (int nt = 0; nt < 8; ++nt)                        \
            acc[nt] = (ffrag){0.f, 0.f, 0.f, 0.f};                              \
        _Pragma("unroll") for (int s = 0; s < 9; ++s) {                         \
            const int dy = s / 3, dx = s - dy * 3;                              \
            int t = jj + dy; if (t >= 5) t -= 5;                                \
            const unsigned short* slabp = &xs[t * 8192];                        \
            _Pragma("unroll") for (int ks = 0; ks < 2; ++ks) {                  \
                const int o = ks * 4 + lq;                                      \
                _Pragma("unroll") for (int nt = 0; nt < 8; ++nt) {              \
                    int colx = nt * 16 + l16 + dx;                              \
                    if (colx > 127) colx = 127;                                 \
                    const bfrag bf = *(const bfrag*)&slabp[(colx * 8 + (o ^ (colx & 7))) * 8]; \
                    acc[nt] = __builtin_amdgcn_mfma_f32_16x16x32_bf16(a[s][ks], bf, acc[nt], 0, 0, 0); \
                }                                                               \
            }                                                                   \
        }                                                                       \
        if (jj + 2 <= nunits) {                                                 \
            int tw = jj + 3; if (tw >= 5) tw -= 5;                              \
            stage_write(&xs[tw * 8192], VCUR, st_o, st_cg);                     \
            asm volatile("s_waitcnt lgkmcnt(0)" ::: "memory");                  \
            __builtin_amdgcn_s_barrier();                                       \
            __builtin_amdgcn_sched_barrier(0);                                  \
        }                                                                       \
        const int oy = y0 + jj;                                                 \
        _Pragma("unroll") for (int r = 0; r < 4; ++r) {                         \
            float* op = out + ((size_t)(b * 64 + wave * 16 + lq * 4 + r) * HO + oy) * WO; \
            const float bvv = bv[r];                                            \
            _Pragma("unroll") for (int nt = 0; nt < 8; ++nt) {                  \
                const int ox = nt * 16 + l16;                                   \
                if (ox < WO) op[ox] = acc[nt][r] + bvv;                         \
            }                                                                   \
        }                                                                       \
    } while (0)

    for (int j = 0; j < nunits; j += 2) {
        UNIT(j, vA, vB);        // even unit: consume vA, prefetch into vB
        UNIT(j + 1, vB, vA);    // odd unit:  consume vB, prefetch into vA
    }
#undef UNIT
}

extern "C" void kernel_launch(void* const* d_in, const int* in_sizes, int n_in,
                              void* d_out, int out_size, void* d_ws, size_t ws_size,
                              hipStream_t stream) {
    const float* x    = (const float*)d_in[0];
    const float* w    = (const float*)d_in[1];
    const float* bias = (const float*)d_in[2];
    float* out        = (float*)d_out;

    unsigned short* w_t = (unsigned short*)d_ws;   // 1,179,648 B

    wt_prepass<<<dim3(589824 / 256), dim3(256), 0, stream>>>(w, w_t);
    dynconv_fused<<<dim3(32, BATCH), dim3(256), 0, stream>>>(x, w_t, bias, out);
}

// Round 5
// 152.212 us; speedup vs baseline: 1.0220x; 1.0220x over previous
//
#include <hip/hip_runtime.h>
#include <hip/hip_bf16.h>

#define BATCH 16
#define CI 64
#define CO 64
#define H 128
#define W 128
#define HO 126
#define WO 126
#define HW (H * W)

typedef short bfrag __attribute__((ext_vector_type(8)));   // 8 bf16 = 4 VGPRs
typedef float ffrag __attribute__((ext_vector_type(4)));   // 4 fp32 acc

static __device__ __forceinline__ unsigned short f2bf(float f) {
    unsigned u = __float_as_uint(f);
    u += 0x7fffu + ((u >> 16) & 1u);      // RNE
    return (unsigned short)(u >> 16);
}

// prepass: w[b][co][ci][dy][dx] fp32 -> w_t[b][s][co][ci] bf16  (s = dy*3+dx)
__global__ void wt_prepass(const float* __restrict__ w, unsigned short* __restrict__ w_t) {
    int i = blockIdx.x * 256 + threadIdx.x;          // 589824 total
    int ci = i & 63;
    int co = (i >> 6) & 63;
    int bs = i >> 12;
    int b = bs / 9, s = bs - b * 9;
    w_t[i] = f2bf(w[(((b * 64 + co) * 64 + ci) * 9) + s]);
}

// cvt + swizzled LDS write of one staged row fragment (R2/R3-verified:
// SQ_LDS_BANK_CONFLICT == 0 on both the ds_write and ds_read sides).
static __device__ __forceinline__ void stage_write(unsigned short* __restrict__ slabp,
                                                   const float4* __restrict__ v,
                                                   int st_o, int st_cg) {
    #pragma unroll
    for (int k = 0; k < 4; ++k) {
        const int col = st_cg * 4 + k;
        unsigned int u[4];
        #pragma unroll
        for (int e = 0; e < 4; ++e) {
            __hip_bfloat162 h2 = __float22bfloat162_rn(make_float2(
                ((const float*)&v[2 * e])[k], ((const float*)&v[2 * e + 1])[k]));
            u[e] = *(unsigned int*)&h2;          // low = even ci
        }
        *(uint4*)&slabp[(col * 8 + (st_o ^ (col & 7))) * 8] = *(const uint4*)u;
    }
}

// Ring-pipelined dynconv, distance-2 prefetch, SPILL-FIXED (R5):
//  - R4 post-mortem: LLVM targeted the 128-VGPR occupancy bucket (despite
//    __launch_bounds__(256,2) being only a MIN) and spilled vA/vB -> ~50 MB
//    scratch VMEM traffic whose reloads drained the vmcnt queue every unit.
//    amdgpu_waves_per_eu(2,2) clamps the allocator to the 2-waves/EU budget
//    (256 VGPRs); live set ~204 fits, no spill.  VGPR_Count ~200 is the tell.
//  - ring back to 4 slabs / 64 KB (R3-proven 2 blocks/CU): the distance-2 row
//    lives in REGISTERS, so only rows j..j+2 (read) + j+3 (stage_write) need
//    LDS concurrently; overwritten row j-1 was last read one barrier ago.
//  - schedule per unit j: issue loads(row j+4) -> compute row j (pure
//    ds_read+MFMA) -> stage_write row j+3 (consumes loads issued at unit j-1,
//    a full unit of service time; counted vmcnt(36), never a drain) ->
//    lgkm-only s_barrier -> stores row j (drain under next unit's compute).
__launch_bounds__(256)
__attribute__((amdgpu_waves_per_eu(2, 2)))
__global__ void dynconv_fused(const float* __restrict__ x,
                              const unsigned short* __restrict__ w_t,
                              const float* __restrict__ bias,
                              float* __restrict__ out) {
    __shared__ __align__(16) unsigned short xs[4 * 8192];   // 4 row-slabs x 16 KB

    const int tid = threadIdx.x;
    const int gx  = blockIdx.x;              // 0..31 row-ranges
    const int b   = blockIdx.y;
    const int y0  = gx * 4;
    const int nunits = (gx == 31) ? 2 : 4;   // 126 output rows total

    const int wave = tid >> 6, lane = tid & 63;
    const int l16 = lane & 15, lq = lane >> 4;

    // staging role: o fast, col-quad slow
    const int st_o  = tid & 7;
    const int st_cg = tid >> 3;              // 0..31

    const float* stp = x + (size_t)b * CI * HW + (size_t)(st_o * 8) * HW + st_cg * 4;

    // ---- A-frag preload: all 9 shifts x 2 ks for this wave's co-quarter
    const bfrag* wtb = (const bfrag*)w_t + (size_t)(b * 9) * 512;
    const int co_b = wave * 16 + l16;
    bfrag a[9][2];
    #pragma unroll
    for (int s = 0; s < 9; ++s)
        #pragma unroll
        for (int ks = 0; ks < 2; ++ks)
            a[s][ks] = wtb[s * 512 + co_b * 8 + ks * 4 + lq];

    float bv[4];
    #pragma unroll
    for (int r = 0; r < 4; ++r)
        bv[r] = bias[b * 64 + wave * 16 + lq * 4 + r];

    float4 vA[8], vB[8];

    // ---- prologue: stage rows y0..y0+2 into slabs 0..2; prefetch row y0+3->vA
    {
        float4 v[3][8];
        #pragma unroll
        for (int rr = 0; rr < 3; ++rr) {
            const float* p = stp + (size_t)(y0 + rr) * W;
            #pragma unroll
            for (int e = 0; e < 8; ++e) v[rr][e] = *(const float4*)(p + (size_t)e * HW);
        }
        {   // distance-2 prefetch issued before the cvt waits on the rows above
            const float* p = stp + (size_t)(y0 + 3) * W;
            #pragma unroll
            for (int e = 0; e < 8; ++e) vA[e] = *(const float4*)(p + (size_t)e * HW);
        }
        #pragma unroll
        for (int rr = 0; rr < 3; ++rr)
            stage_write(&xs[rr * 8192], v[rr], st_o, st_cg);
    }
    asm volatile("s_waitcnt lgkmcnt(0)" ::: "memory");
    __builtin_amdgcn_s_barrier();
    __builtin_amdgcn_sched_barrier(0);

// one output-row unit: prefetch row jj+4 into VNEXT, compute row jj from slabs
// (jj..jj+2)&3, stage_write row jj+3 from VCUR into slab (jj+3)&3, barrier,
// store row jj.
#define UNIT(J_, VCUR, VNEXT)                                                   \
    do {                                                                        \
        const int jj = (J_);                                                    \
        if (jj + 3 <= nunits) {                                                 \
            const float* p = stp + (size_t)(y0 + jj + 4) * W;                   \
            _Pragma("unroll") for (int e = 0; e < 8; ++e)                       \
                VNEXT[e] = *(const float4*)(p + (size_t)e * HW);                \
        }                                                                       \
        __builtin_amdgcn_sched_barrier(0);                                      \
        ffrag acc[8];                                                           \
        _Pragma("unroll") for (int nt = 0; nt < 8; ++nt)                        \
            acc[nt] = (ffrag){0.f, 0.f, 0.f, 0.f};                              \
        _Pragma("unroll") for (int s = 0; s < 9; ++s) {                         \
            const int dy = s / 3, dx = s - dy * 3;                              \
            const unsigned short* slabp = &xs[((jj + dy) & 3) * 8192];          \
            _Pragma("unroll") for (int ks = 0; ks < 2; ++ks) {                  \
                const int o = ks * 4 + lq;                                      \
                _Pragma("unroll") for (int nt = 0; nt < 8; ++nt) {              \
                    int colx = nt * 16 + l16 + dx;                              \
                    if (colx > 127) colx = 127;                                 \
                    const bfrag bf = *(const bfrag*)&slabp[(colx * 8 + (o ^ (colx & 7))) * 8]; \
                    acc[nt] = __builtin_amdgcn_mfma_f32_16x16x32_bf16(a[s][ks], bf, acc[nt], 0, 0, 0); \
                }                                                               \
            }                                                                   \
        }                                                                       \
        if (jj + 2 <= nunits) {                                                 \
            stage_write(&xs[((jj + 3) & 3) * 8192], VCUR, st_o, st_cg);         \
            asm volatile("s_waitcnt lgkmcnt(0)" ::: "memory");                  \
            __builtin_amdgcn_s_barrier();                                       \
            __builtin_amdgcn_sched_barrier(0);                                  \
        }                                                                       \
        const int oy = y0 + jj;                                                 \
        _Pragma("unroll") for (int r = 0; r < 4; ++r) {                         \
            float* op = out + ((size_t)(b * 64 + wave * 16 + lq * 4 + r) * HO + oy) * WO; \
            const float bvv = bv[r];                                            \
            _Pragma("unroll") for (int nt = 0; nt < 8; ++nt) {                  \
                const int ox = nt * 16 + l16;                                   \
                if (ox < WO) op[ox] = acc[nt][r] + bvv;                         \
            }                                                                   \
        }                                                                       \
    } while (0)

    for (int j = 0; j < nunits; j += 2) {
        UNIT(j, vA, vB);        // even unit: consume vA, prefetch into vB
        UNIT(j + 1, vB, vA);    // odd unit:  consume vB, prefetch into vA
    }
#undef UNIT
}

extern "C" void kernel_launch(void* const* d_in, const int* in_sizes, int n_in,
                              void* d_out, int out_size, void* d_ws, size_t ws_size,
                              hipStream_t stream) {
    const float* x    = (const float*)d_in[0];
    const float* w    = (const float*)d_in[1];
    const float* bias = (const float*)d_in[2];
    float* out        = (float*)d_out;

    unsigned short* w_t = (unsigned short*)d_ws;   // 1,179,648 B

    wt_prepass<<<dim3(589824 / 256), dim3(256), 0, stream>>>(w, w_t);
    dynconv_fused<<<dim3(32, BATCH), dim3(256), 0, stream>>>(x, w_t, bias, out);
}

// Round 6
// 146.928 us; speedup vs baseline: 1.0588x; 1.0360x over previous
//
#include <hip/hip_runtime.h>
#include <hip/hip_bf16.h>

#define BATCH 16
#define CI 64
#define CO 64
#define H 128
#define W 128
#define HO 126
#define WO 126
#define HW (H * W)

typedef short bfrag __attribute__((ext_vector_type(8)));   // 8 bf16 = 4 VGPRs
typedef float ffrag __attribute__((ext_vector_type(4)));   // 4 fp32 acc

typedef __attribute__((address_space(1))) const unsigned char g_byte;
typedef __attribute__((address_space(3))) unsigned char l_byte;

static __device__ __forceinline__ unsigned short f2bf(float f) {
    unsigned u = __float_as_uint(f);
    u += 0x7fffu + ((u >> 16) & 1u);      // RNE
    return (unsigned short)(u >> 16);
}

// prepass: w[b][co][ci][dy][dx] fp32 -> w_t[b][s][co][ci] bf16  (s = dy*3+dx)
__global__ void wt_prepass(const float* __restrict__ w, unsigned short* __restrict__ w_t) {
    int i = blockIdx.x * 256 + threadIdx.x;          // 589824 total
    int ci = i & 63;
    int co = (i >> 6) & 63;
    int bs = i >> 12;
    int b = bs / 9, s = bs - b * 9;
    w_t[i] = f2bf(w[(((b * 64 + co) * 64 + ci) * 9) + s]);
}

// prepass: x fp32 NCHW -> x_t bf16, swizzled chunk layout, one block per
// (row, b).  x_t row = 1024 chunks x 16 B; chunk c = col*8 + (o ^ (col&7))
// holds ci o*8..o*8+7 (low = even ci) of column col — EXACTLY the layout the
// fused kernel's ds_read side expects, so global_load_lds can do an identity
// copy (linear lane order) into each LDS slab.
__global__ void xt_prepass(const float* __restrict__ x, unsigned short* __restrict__ x_t) {
    __shared__ __align__(16) float lf[64 * 132];     // padded fp32 tile
    const int row = blockIdx.x, b = blockIdx.y, t = threadIdx.x;

    const float* xb = x + (size_t)b * CI * HW + (size_t)row * W;
    {   // phase 1: coalesced fp32 loads (32 lanes x 16B runs per ci)
        const int ci0 = t >> 5, c4 = (t & 31) * 4;
        #pragma unroll
        for (int p = 0; p < 8; ++p) {
            const int ci = p * 8 + ci0;
            float4 v = *(const float4*)(xb + (size_t)ci * HW + c4);
            *(float4*)&lf[ci * 132 + c4] = v;
        }
    }
    __syncthreads();
    // phase 2: pack chunks; consecutive threads -> consecutive 16B writes
    unsigned short* xrow = x_t + ((size_t)(b * 128) + row) * 8192;
    #pragma unroll
    for (int cc = 0; cc < 4; ++cc) {
        const int c = cc * 256 + t;
        const int col = c >> 3, s8 = c & 7, o = s8 ^ (col & 7);
        unsigned int u[4];
        #pragma unroll
        for (int e = 0; e < 4; ++e) {
            float f0 = lf[(o * 8 + 2 * e) * 132 + col];
            float f1 = lf[(o * 8 + 2 * e + 1) * 132 + col];
            __hip_bfloat162 h2 = __float22bfloat162_rn(make_float2(f0, f1));
            u[e] = *(unsigned int*)&h2;              // low = even ci
        }
        *(uint4*)&xrow[(size_t)c * 8] = *(const uint4*)u;
    }
}

// Ring-pipelined dynconv, global_load_lds staging (R6):
//  - R4/R5 post-mortem: allocator pins 128 VGPR and spills the reg-staging
//    buffers (WRITE_SIZE +32 MB scratch) regardless of occupancy hints.
//    Fix: ZERO staging registers — x_t is pre-converted/pre-swizzled, each
//    16 KB row is staged by 16 global_load_lds_dwordx4 (4/wave), identity
//    copy.  Live set = a[72] + acc[32] + misc ~ 120 < 128 -> cannot spill.
//  - LDS ring of 5 slabs (80 KB; 2 blocks/CU = 160 KB exactly). Row r ->
//    slab r%5.  Unit j: compute row j (slabs j..j+2) -> lgkm barrier (slab
//    j%5 now dead) -> issue loads row j+5 -> slab j%5 -> counted vmcnt ->
//    barrier -> stores row j.  Distance-2: loads consumed 2 units after issue.
//  - counted vmcnt (m201 pattern): at unit j wait, ops younger than
//    loads(j+4) = stores(j-1) [32 dword] + loads(j+5) [4] = 36; in-order
//    retirement => vmcnt(36) guarantees rows <= j+4 landed without draining
//    the in-flight stores/loads.  Unit 0 (no stores yet) uses exact vmcnt(8).
__launch_bounds__(256)
__global__ void dynconv_fused(const unsigned short* __restrict__ x_t,
                              const unsigned short* __restrict__ w_t,
                              const float* __restrict__ bias,
                              float* __restrict__ out) {
    __shared__ __align__(16) unsigned short xs[5 * 8192];   // 5 slabs x 16 KB

    const int tid = threadIdx.x;
    const int gx  = blockIdx.x;              // 0..31 row-ranges
    const int b   = blockIdx.y;
    const int y0  = gx * 4;
    const int nu  = (gx == 31) ? 2 : 4;      // 126 output rows total
    const int rmaxl = nu + 1;                // last real local x-row

    const int wave = tid >> 6, lane = tid & 63;
    const int l16 = lane & 15, lq = lane >> 4;

    // ---- A-frag preload: all 9 shifts x 2 ks for this wave's co-quarter
    const bfrag* wtb = (const bfrag*)w_t + (size_t)(b * 9) * 512;
    const int co_b = wave * 16 + l16;
    bfrag a[9][2];
    #pragma unroll
    for (int s = 0; s < 9; ++s)
        #pragma unroll
        for (int ks = 0; ks < 2; ++ks)
            a[s][ks] = wtb[s * 512 + co_b * 8 + ks * 4 + lq];

    float bv[4];
    #pragma unroll
    for (int r = 0; r < 4; ++r)
        bv[r] = bias[b * 64 + wave * 16 + lq * 4 + r];

    // x_t base for this (b, y0); row stride = 8192 shorts = 16 KB
    const unsigned short* xtb = x_t + ((size_t)(b * 128) + y0) * 8192;
    const int lnoff = wave * 4096 + lane * 16;          // byte offset in row/slab

// stage local row RL into slab SL: 4 x global_load_lds dwordx4 per wave,
// wave-uniform LDS base + lane*16 (identity copy of the pre-swizzled row).
#define STAGE_ROW(RL, SL)                                                       \
    do {                                                                        \
        const char* gsrc_ = (const char*)(xtb + (size_t)(RL) * 8192) + lnoff;   \
        l_byte* ldst_ = (l_byte*)((char*)&xs[(SL) * 8192] + wave * 4096);       \
        _Pragma("unroll") for (int q_ = 0; q_ < 4; ++q_)                        \
            __builtin_amdgcn_global_load_lds((g_byte*)(gsrc_ + q_ * 1024),      \
                                             ldst_ + q_ * 1024, 16, 0, 0);      \
    } while (0)

    // ---- prologue: rows 0..4 -> slabs 0..4 (clamped rows land in dead slabs)
    #pragma unroll
    for (int r = 0; r < 5; ++r) {
        const int rl = (r <= rmaxl) ? r : rmaxl;
        STAGE_ROW(rl, r);
    }
    asm volatile("s_waitcnt vmcnt(8)" ::: "memory");    // rows 0..2 landed
    __builtin_amdgcn_s_barrier();
    __builtin_amdgcn_sched_barrier(0);

    for (int j = 0; j < nu; ++j) {
        // 1. compute row j from slabs (j..j+2)%5 — pure ds_read + MFMA
        ffrag acc[8];
        #pragma unroll
        for (int nt = 0; nt < 8; ++nt) acc[nt] = (ffrag){0.f, 0.f, 0.f, 0.f};

        #pragma unroll
        for (int s = 0; s < 9; ++s) {
            const int dy = s / 3, dx = s - dy * 3;
            int t = j + dy; if (t >= 5) t -= 5;
            const unsigned short* slabp = &xs[t * 8192];
            #pragma unroll
            for (int ks = 0; ks < 2; ++ks) {
                const int o = ks * 4 + lq;
                #pragma unroll
                for (int nt = 0; nt < 8; ++nt) {
                    int colx = nt * 16 + l16 + dx;
                    if (colx > 127) colx = 127;    // clamped lanes -> discarded cols
                    const bfrag bf = *(const bfrag*)&slabp[(colx * 8 + (o ^ (colx & 7))) * 8];
                    acc[nt] = __builtin_amdgcn_mfma_f32_16x16x32_bf16(a[s][ks], bf, acc[nt], 0, 0, 0);
                }
            }
        }

        // 2. all waves' reads of slab j%5 done -> it is reusable
        asm volatile("s_waitcnt lgkmcnt(0)" ::: "memory");
        __builtin_amdgcn_s_barrier();
        __builtin_amdgcn_sched_barrier(0);

        // 3. issue loads for row j+5 (clamped dups land in the dead slab j%5)
        {
            const int rl = (j + 5 <= rmaxl) ? (j + 5) : rmaxl;
            STAGE_ROW(rl, j);
        }
        __builtin_amdgcn_sched_barrier(0);

        // 4. counted wait: rows <= j+4 landed (loads(j+4) older than the
        //    36 youngest = stores(j-1)[32] + loads(j+5)[4]); unit 0 exact.
        if (j == 0) { asm volatile("s_waitcnt vmcnt(8)"  ::: "memory"); }
        else        { asm volatile("s_waitcnt vmcnt(36)" ::: "memory"); }
        __builtin_amdgcn_s_barrier();
        __builtin_amdgcn_sched_barrier(0);

        // 5. stores row j (32 predicated dwords/wave) — drain lazily
        const int oy = y0 + j;
        #pragma unroll
        for (int r = 0; r < 4; ++r) {
            float* op = out + ((size_t)(b * 64 + wave * 16 + lq * 4 + r) * HO + oy) * WO;
            const float bvv = bv[r];
            #pragma unroll
            for (int nt = 0; nt < 8; ++nt) {
                const int ox = nt * 16 + l16;
                if (ox < WO) op[ox] = acc[nt][r] + bvv;
            }
        }
    }
#undef STAGE_ROW
}

extern "C" void kernel_launch(void* const* d_in, const int* in_sizes, int n_in,
                              void* d_out, int out_size, void* d_ws, size_t ws_size,
                              hipStream_t stream) {
    const float* x    = (const float*)d_in[0];
    const float* w    = (const float*)d_in[1];
    const float* bias = (const float*)d_in[2];
    float* out        = (float*)d_out;

    unsigned short* w_t = (unsigned short*)d_ws;                       // 1,179,648 B
    unsigned short* x_t = (unsigned short*)((char*)d_ws + 1179648);    // 33,554,432 B

    wt_prepass<<<dim3(589824 / 256), dim3(256), 0, stream>>>(w, w_t);
    xt_prepass<<<dim3(128, BATCH), dim3(256), 0, stream>>>(x, x_t);
    dynconv_fused<<<dim3(32, BATCH), dim3(256), 0, stream>>>(x_t, w_t, bias, out);
}